// Round 1
// baseline (2593.331 us; speedup 1.0000x reference)
//
#include <hip/hip_runtime.h>
#include <math.h>

#define SEQ 128
#define BATCH 32
#define EDIM 300
#define HDIM 200
#define G4 800      // 4*H
#define NGATE 1600  // 2 dirs * 4 * H

// ------------------------------------------------------------------
// K1: embedding gather  X0[t][b][e] = emb[words[b][t]][e]
// ------------------------------------------------------------------
__global__ void k_gather(const int* __restrict__ words,
                         const float* __restrict__ emb,
                         float* __restrict__ X0)
{
    int row = blockIdx.x;          // row = t*32 + b
    int t = row >> 5;
    int b = row & 31;
    int w = words[b * SEQ + t];
    const float* src = emb + (size_t)w * EDIM;
    float* dst = X0 + (size_t)row * EDIM;
    for (int e = threadIdx.x; e < EDIM; e += blockDim.x) dst[e] = src[e];
}

// ------------------------------------------------------------------
// K2/K4: C[M x N] = A[M x K] @ B[N x K]^T + bias[N]   (f32, tiled)
// BM=BN=64, BK=32, 256 threads, 4x4 per thread
// ------------------------------------------------------------------
#define BM 64
#define BN 64
#define BK 32
#define LDT 72

__global__ __launch_bounds__(256)
void k_gemm_bias(const float* __restrict__ A,
                 const float* __restrict__ Bw,
                 const float* __restrict__ bias,
                 float* __restrict__ C,
                 int M, int N, int K)
{
    __shared__ __align__(16) float As[BK][LDT];
    __shared__ __align__(16) float Bs[BK][LDT];
    int tid = threadIdx.x;
    int tx = tid & 15, ty = tid >> 4;
    int bm = blockIdx.y * BM, bn = blockIdx.x * BN;
    float acc[4][4] = {};
    for (int k0 = 0; k0 < K; k0 += BK) {
#pragma unroll
        for (int i = 0; i < 8; ++i) {
            int idx = i * 256 + tid;
            int m = idx >> 5, k = idx & 31;
            bool ok = (k0 + k) < K;
            As[k][m] = ok ? A[(size_t)(bm + m) * K + k0 + k] : 0.f;
            Bs[k][m] = ok ? Bw[(size_t)(bn + m) * K + k0 + k] : 0.f;
        }
        __syncthreads();
#pragma unroll
        for (int kk = 0; kk < BK; ++kk) {
            float4 av = *(const float4*)&As[kk][ty * 4];
            float4 bv = *(const float4*)&Bs[kk][tx * 4];
            float a0 = av.x, a1 = av.y, a2 = av.z, a3 = av.w;
            float b0 = bv.x, b1 = bv.y, b2 = bv.z, b3 = bv.w;
            acc[0][0] += a0 * b0; acc[0][1] += a0 * b1; acc[0][2] += a0 * b2; acc[0][3] += a0 * b3;
            acc[1][0] += a1 * b0; acc[1][1] += a1 * b1; acc[1][2] += a1 * b2; acc[1][3] += a1 * b3;
            acc[2][0] += a2 * b0; acc[2][1] += a2 * b1; acc[2][2] += a2 * b2; acc[2][3] += a2 * b3;
            acc[3][0] += a3 * b0; acc[3][1] += a3 * b1; acc[3][2] += a3 * b2; acc[3][3] += a3 * b3;
        }
        __syncthreads();
    }
#pragma unroll
    for (int i = 0; i < 4; ++i) {
        int m = bm + ty * 4 + i;
#pragma unroll
        for (int j = 0; j < 4; ++j) {
            int n = bn + tx * 4 + j;
            C[(size_t)m * N + n] = acc[i][j] + bias[n];
        }
    }
}

// ------------------------------------------------------------------
// K3/K5: recurrent BiLSTM layer.
// grid = 64 blocks: block = (dir d, batch b). 832 threads.
// Thread r < 800 owns gate-row r: U[r][0:200] held in 200 VGPRs
// (fully unrolled static indexing). h broadcast from LDS (float4,
// same-address -> conflict-free broadcast).
// Xg layout: (S, B, 1600) = precomputed x@Wih^T + bias, per dir.
// Hout layout: (S, B, 400) [fwd 0:200 | bwd 200:400]
// ------------------------------------------------------------------
__global__ __launch_bounds__(832)
void k_lstm(const float* __restrict__ Xg,
            const float* __restrict__ Whh,   // (2, 800, 200)
            float* __restrict__ Hout)
{
    int blk = blockIdx.x;      // 0..63
    int d = blk >> 5;          // direction
    int b = blk & 31;          // batch
    int r = threadIdx.x;       // gate row

    __shared__ __align__(16) float h_lds[HDIM];
    __shared__ float g_lds[G4];

    float u[HDIM];
    if (r < G4) {
        const float4* Urow = (const float4*)(Whh + ((size_t)d * G4 + r) * HDIM);
#pragma unroll
        for (int q = 0; q < HDIM / 4; ++q) {
            float4 uv = Urow[q];
            u[4 * q + 0] = uv.x; u[4 * q + 1] = uv.y;
            u[4 * q + 2] = uv.z; u[4 * q + 3] = uv.w;
        }
    }
    if (r < HDIM) h_lds[r] = 0.f;
    float c = 0.f;
    __syncthreads();

#pragma unroll 1
    for (int t = 0; t < SEQ; ++t) {
        int tt = d ? (SEQ - 1 - t) : t;
        if (r < G4) {
            float acc = Xg[((size_t)tt * BATCH + b) * NGATE + d * G4 + r];
#pragma unroll
            for (int q = 0; q < HDIM / 4; ++q) {
                float4 hv = *(const float4*)&h_lds[4 * q];
                acc += u[4 * q + 0] * hv.x;
                acc += u[4 * q + 1] * hv.y;
                acc += u[4 * q + 2] * hv.z;
                acc += u[4 * q + 3] * hv.w;
            }
            g_lds[r] = acc;
        }
        __syncthreads();
        if (r < HDIM) {
            float gi = g_lds[r];
            float gf = g_lds[HDIM + r];
            float gg = g_lds[2 * HDIM + r];
            float go = g_lds[3 * HDIM + r];
            float si = 1.f / (1.f + __expf(-gi));
            float sf = 1.f / (1.f + __expf(-gf));
            float so = 1.f / (1.f + __expf(-go));
            c = sf * c + si * tanhf(gg);
            float hh = so * tanhf(c);
            h_lds[r] = hh;
            Hout[((size_t)tt * BATCH + b) * (2 * HDIM) + d * HDIM + r] = hh;
        }
        __syncthreads();
    }
}

// ------------------------------------------------------------------
// K6: out[b][s][o] = sigmoid(H1[s][b][:] . Wo[o][:] + bo[o])
// ------------------------------------------------------------------
__global__ void k_out(const float* __restrict__ H1,
                      const float* __restrict__ Wo,
                      const float* __restrict__ bo,
                      float* __restrict__ out)
{
    int idx = blockIdx.x * blockDim.x + threadIdx.x;
    if (idx >= BATCH * SEQ * 17) return;
    int o = idx % 17;
    int bs = idx / 17;
    int b = bs >> 7;      // /128
    int s = bs & 127;
    const float* hrow = H1 + ((size_t)(s * BATCH + b)) * (2 * HDIM);
    const float* wrow = Wo + (size_t)o * (2 * HDIM);
    float acc = bo[o];
#pragma unroll 4
    for (int j = 0; j < 2 * HDIM; ++j) acc += hrow[j] * wrow[j];
    out[idx] = 1.f / (1.f + __expf(-acc));
}

// ------------------------------------------------------------------
extern "C" void kernel_launch(void* const* d_in, const int* in_sizes, int n_in,
                              void* d_out, int out_size, void* d_ws, size_t ws_size,
                              hipStream_t stream)
{
    const int*   words = (const int*)d_in[0];
    // d_in[1] chars, d_in[2] lens: dead code in the reference
    const float* emb   = (const float*)d_in[3];
    // d_in[4..6]: char conv params, dead
    const float* Wih0  = (const float*)d_in[7];
    const float* Whh0  = (const float*)d_in[8];
    const float* b0    = (const float*)d_in[9];
    const float* Wih1  = (const float*)d_in[10];
    const float* Whh1  = (const float*)d_in[11];
    const float* b1    = (const float*)d_in[12];
    const float* Wo    = (const float*)d_in[13];
    const float* bo    = (const float*)d_in[14];
    float* out = (float*)d_out;

    char* ws = (char*)d_ws;
    const size_t X0_OFF = 0;
    const size_t XG_OFF = X0_OFF + (size_t)SEQ * BATCH * EDIM * 4;          // 4.9 MB
    const size_t H0_OFF = XG_OFF + (size_t)SEQ * BATCH * NGATE * 4;         // +26.2 MB
    const size_t H1_OFF = H0_OFF + (size_t)SEQ * BATCH * 2 * HDIM * 4;      // +6.6 MB
    float* X0 = (float*)(ws + X0_OFF);
    float* Xg = (float*)(ws + XG_OFF);
    float* H0 = (float*)(ws + H0_OFF);
    float* H1 = (float*)(ws + H1_OFF);

    // 1. gather embeddings -> X0 (S, B, 300)
    k_gather<<<SEQ * BATCH, 128, 0, stream>>>(words, emb, X0);

    // 2. layer-0 input GEMM: Xg = X0 @ Wih0^T + b0   (4096 x 1600, K=300)
    dim3 gemm_grid(NGATE / BN, (SEQ * BATCH) / BM);
    k_gemm_bias<<<gemm_grid, 256, 0, stream>>>(X0, Wih0, b0, Xg,
                                               SEQ * BATCH, NGATE, EDIM);

    // 3. layer-0 recurrence -> H0 (S, B, 400)
    k_lstm<<<64, 832, 0, stream>>>(Xg, Whh0, H0);

    // 4. layer-1 input GEMM: Xg = H0 @ Wih1^T + b1   (4096 x 1600, K=400)
    k_gemm_bias<<<gemm_grid, 256, 0, stream>>>(H0, Wih1, b1, Xg,
                                               SEQ * BATCH, NGATE, 2 * HDIM);

    // 5. layer-1 recurrence -> H1
    k_lstm<<<64, 832, 0, stream>>>(Xg, Whh1, H1);

    // 6. output head
    int nout = BATCH * SEQ * 17;
    k_out<<<(nout + 255) / 256, 256, 0, stream>>>(H1, Wo, bo, out);
}

// Round 2
// 2565.090 us; speedup vs baseline: 1.0110x; 1.0110x over previous
//
#include <hip/hip_runtime.h>
#include <math.h>

#define SEQ 128
#define BATCH 32
#define EDIM 300
#define HDIM 200
#define G4 800      // 4*H
#define NGATE 1600  // 2 dirs * 4 * H

// ------------------------------------------------------------------
// K1: embedding gather  X0[t][b][e] = emb[words[b][t]][e]
// ------------------------------------------------------------------
__global__ void k_gather(const int* __restrict__ words,
                         const float* __restrict__ emb,
                         float* __restrict__ X0)
{
    int row = blockIdx.x;          // row = t*32 + b
    int t = row >> 5;
    int b = row & 31;
    int w = words[b * SEQ + t];
    const float* src = emb + (size_t)w * EDIM;
    float* dst = X0 + (size_t)row * EDIM;
    for (int e = threadIdx.x; e < EDIM; e += blockDim.x) dst[e] = src[e];
}

// ------------------------------------------------------------------
// K2/K4: C[M x N] = A[M x K] @ B[N x K]^T + bias[N]   (f32, tiled)
// ------------------------------------------------------------------
#define BM 64
#define BN 64
#define BK 32
#define LDT 72

__global__ __launch_bounds__(256)
void k_gemm_bias(const float* __restrict__ A,
                 const float* __restrict__ Bw,
                 const float* __restrict__ bias,
                 float* __restrict__ C,
                 int M, int N, int K)
{
    __shared__ __align__(16) float As[BK][LDT];
    __shared__ __align__(16) float Bs[BK][LDT];
    int tid = threadIdx.x;
    int tx = tid & 15, ty = tid >> 4;
    int bm = blockIdx.y * BM, bn = blockIdx.x * BN;
    float acc[4][4] = {};
    for (int k0 = 0; k0 < K; k0 += BK) {
#pragma unroll
        for (int i = 0; i < 8; ++i) {
            int idx = i * 256 + tid;
            int m = idx >> 5, k = idx & 31;
            bool ok = (k0 + k) < K;
            As[k][m] = ok ? A[(size_t)(bm + m) * K + k0 + k] : 0.f;
            Bs[k][m] = ok ? Bw[(size_t)(bn + m) * K + k0 + k] : 0.f;
        }
        __syncthreads();
#pragma unroll
        for (int kk = 0; kk < BK; ++kk) {
            float4 av = *(const float4*)&As[kk][ty * 4];
            float4 bv = *(const float4*)&Bs[kk][tx * 4];
            float a0 = av.x, a1 = av.y, a2 = av.z, a3 = av.w;
            float b0 = bv.x, b1 = bv.y, b2 = bv.z, b3 = bv.w;
            acc[0][0] += a0 * b0; acc[0][1] += a0 * b1; acc[0][2] += a0 * b2; acc[0][3] += a0 * b3;
            acc[1][0] += a1 * b0; acc[1][1] += a1 * b1; acc[1][2] += a1 * b2; acc[1][3] += a1 * b3;
            acc[2][0] += a2 * b0; acc[2][1] += a2 * b1; acc[2][2] += a2 * b2; acc[2][3] += a2 * b3;
            acc[3][0] += a3 * b0; acc[3][1] += a3 * b1; acc[3][2] += a3 * b2; acc[3][3] += a3 * b3;
        }
        __syncthreads();
    }
#pragma unroll
    for (int i = 0; i < 4; ++i) {
        int m = bm + ty * 4 + i;
#pragma unroll
        for (int j = 0; j < 4; ++j) {
            int n = bn + tx * 4 + j;
            C[(size_t)m * N + n] = acc[i][j] + bias[n];
        }
    }
}

// ------------------------------------------------------------------
// K3/K5: recurrent BiLSTM layer.
// grid = 64 blocks: block = (dir d, batch b). 832 threads (13 waves).
// Thread r < 800 owns gate-row r. U[r][0:200] is held in 50 NAMED
// float4 registers (u0..u49) -- no array, nothing to spill.
// h broadcast from LDS (same-address float4 reads -> conflict-free).
// ------------------------------------------------------------------
#define REP50(X) \
    X(0)  X(1)  X(2)  X(3)  X(4)  X(5)  X(6)  X(7)  X(8)  X(9)  \
    X(10) X(11) X(12) X(13) X(14) X(15) X(16) X(17) X(18) X(19) \
    X(20) X(21) X(22) X(23) X(24) X(25) X(26) X(27) X(28) X(29) \
    X(30) X(31) X(32) X(33) X(34) X(35) X(36) X(37) X(38) X(39) \
    X(40) X(41) X(42) X(43) X(44) X(45) X(46) X(47) X(48) X(49)

__device__ __forceinline__ float fast_sigmoid(float x) {
    return 1.f / (1.f + __expf(-x));
}
__device__ __forceinline__ float fast_tanh(float x) {
    x = fminf(fmaxf(x, -15.f), 15.f);
    float e = __expf(2.f * x);
    return (e - 1.f) / (e + 1.f);
}

__global__ __launch_bounds__(832)
void k_lstm(const float* __restrict__ Xg,
            const float* __restrict__ Whh,   // (2, 800, 200)
            float* __restrict__ Hout)
{
    int blk = blockIdx.x;      // 0..63
    int d = blk >> 5;          // direction
    int b = blk & 31;          // batch
    int r = threadIdx.x;       // gate row

    __shared__ __align__(16) float h_lds[HDIM];
    __shared__ float g_lds[G4];

    // --- load U row into 50 named float4 registers (clamped row for r>=800,
    //     values never used by those threads) ---
    int rr = (r < G4) ? r : (G4 - 1);
    const float4* Urow = (const float4*)(Whh + ((size_t)d * G4 + rr) * HDIM);
#define U_DECL(i) float4 u##i = Urow[i];
    REP50(U_DECL)
#undef U_DECL

    if (r < HDIM) h_lds[r] = 0.f;
    float c = 0.f;

    // base pointer for this thread's Xg element (stride between steps is
    // BATCH*NGATE floats; direction d walks tt = d ? SEQ-1-t : t)
    const float* xg_ptr = Xg + (size_t)b * NGATE + d * G4 + rr;
    const ptrdiff_t step_stride = (ptrdiff_t)BATCH * NGATE;

    __syncthreads();

    int tt0 = d ? (SEQ - 1) : 0;
    float xg_cur = xg_ptr[(ptrdiff_t)tt0 * step_stride];

#pragma unroll 1
    for (int t = 0; t < SEQ; ++t) {
        int tt = d ? (SEQ - 1 - t) : t;
        int tn = d ? (SEQ - 2 - t) : (t + 1);
        // issue next step's Xg load early (independent of this step)
        float xg_next = (t + 1 < SEQ) ? xg_ptr[(ptrdiff_t)tn * step_stride] : 0.f;

        float acc = xg_cur;
#define U_DOT(i) { float4 hv = *(const float4*)&h_lds[4 * (i)];              \
                   acc += u##i.x * hv.x; acc += u##i.y * hv.y;               \
                   acc += u##i.z * hv.z; acc += u##i.w * hv.w; }
        REP50(U_DOT)
#undef U_DOT
        if (r < G4) g_lds[r] = acc;
        __syncthreads();

        if (r < HDIM) {
            float gi = g_lds[r];
            float gf = g_lds[HDIM + r];
            float gg = g_lds[2 * HDIM + r];
            float go = g_lds[3 * HDIM + r];
            float si = fast_sigmoid(gi);
            float sf = fast_sigmoid(gf);
            float so = fast_sigmoid(go);
            c = sf * c + si * fast_tanh(gg);
            float hh = so * fast_tanh(c);
            h_lds[r] = hh;
            Hout[((size_t)tt * BATCH + b) * (2 * HDIM) + d * HDIM + r] = hh;
        }
        __syncthreads();
        xg_cur = xg_next;
    }
}

// ------------------------------------------------------------------
// K6: out[b][s][o] = sigmoid(H1[s][b][:] . Wo[o][:] + bo[o])
// ------------------------------------------------------------------
__global__ void k_out(const float* __restrict__ H1,
                      const float* __restrict__ Wo,
                      const float* __restrict__ bo,
                      float* __restrict__ out)
{
    int idx = blockIdx.x * blockDim.x + threadIdx.x;
    if (idx >= BATCH * SEQ * 17) return;
    int o = idx % 17;
    int bs = idx / 17;
    int b = bs >> 7;      // /128
    int s = bs & 127;
    const float* hrow = H1 + ((size_t)(s * BATCH + b)) * (2 * HDIM);
    const float* wrow = Wo + (size_t)o * (2 * HDIM);
    float acc = bo[o];
#pragma unroll 4
    for (int j = 0; j < 2 * HDIM; ++j) acc += hrow[j] * wrow[j];
    out[idx] = 1.f / (1.f + __expf(-acc));
}

// ------------------------------------------------------------------
extern "C" void kernel_launch(void* const* d_in, const int* in_sizes, int n_in,
                              void* d_out, int out_size, void* d_ws, size_t ws_size,
                              hipStream_t stream)
{
    const int*   words = (const int*)d_in[0];
    // d_in[1] chars, d_in[2] lens: dead code in the reference
    const float* emb   = (const float*)d_in[3];
    // d_in[4..6]: char conv params, dead
    const float* Wih0  = (const float*)d_in[7];
    const float* Whh0  = (const float*)d_in[8];
    const float* b0    = (const float*)d_in[9];
    const float* Wih1  = (const float*)d_in[10];
    const float* Whh1  = (const float*)d_in[11];
    const float* b1    = (const float*)d_in[12];
    const float* Wo    = (const float*)d_in[13];
    const float* bo    = (const float*)d_in[14];
    float* out = (float*)d_out;

    char* ws = (char*)d_ws;
    const size_t X0_OFF = 0;
    const size_t XG_OFF = X0_OFF + (size_t)SEQ * BATCH * EDIM * 4;          // 4.9 MB
    const size_t H0_OFF = XG_OFF + (size_t)SEQ * BATCH * NGATE * 4;         // +26.2 MB
    const size_t H1_OFF = H0_OFF + (size_t)SEQ * BATCH * 2 * HDIM * 4;      // +6.6 MB
    float* X0 = (float*)(ws + X0_OFF);
    float* Xg = (float*)(ws + XG_OFF);
    float* H0 = (float*)(ws + H0_OFF);
    float* H1 = (float*)(ws + H1_OFF);

    // 1. gather embeddings -> X0 (S, B, 300)
    k_gather<<<SEQ * BATCH, 128, 0, stream>>>(words, emb, X0);

    // 2. layer-0 input GEMM: Xg = X0 @ Wih0^T + b0   (4096 x 1600, K=300)
    dim3 gemm_grid(NGATE / BN, (SEQ * BATCH) / BM);
    k_gemm_bias<<<gemm_grid, 256, 0, stream>>>(X0, Wih0, b0, Xg,
                                               SEQ * BATCH, NGATE, EDIM);

    // 3. layer-0 recurrence -> H0 (S, B, 400)
    k_lstm<<<64, 832, 0, stream>>>(Xg, Whh0, H0);

    // 4. layer-1 input GEMM: Xg = H0 @ Wih1^T + b1   (4096 x 1600, K=400)
    k_gemm_bias<<<gemm_grid, 256, 0, stream>>>(H0, Wih1, b1, Xg,
                                               SEQ * BATCH, NGATE, 2 * HDIM);

    // 5. layer-1 recurrence -> H1
    k_lstm<<<64, 832, 0, stream>>>(Xg, Whh1, H1);

    // 6. output head
    int nout = BATCH * SEQ * 17;
    k_out<<<(nout + 255) / 256, 256, 0, stream>>>(H1, Wo, bo, out);
}

// Round 3
// 646.598 us; speedup vs baseline: 4.0107x; 3.9671x over previous
//
#include <hip/hip_runtime.h>
#include <math.h>

#define SEQ 128
#define BATCH 32
#define EDIM 300
#define HDIM 200
#define G4 800      // 4*H
#define NGATE 1600  // 2 dirs * 4 * H

typedef _Float16 h2t __attribute__((ext_vector_type(2)));

__device__ __forceinline__ h2t u2h(unsigned v) {
    union { unsigned u; h2t h; } c; c.u = v; return c.h;
}

// v_dot2_f32_f16: acc += a.x*b.x + a.y*b.y  (f32 accumulate)
__device__ __forceinline__ float dot2acc(h2t a, h2t b, float c) {
    return __builtin_amdgcn_fdot2(a, b, c, false);
}

__device__ __forceinline__ float fast_sigmoid(float x) {
    return 1.f / (1.f + __expf(-x));
}
__device__ __forceinline__ float fast_tanh(float x) {
    x = fminf(fmaxf(x, -15.f), 15.f);
    float e = __expf(2.f * x);
    return (e - 1.f) / (e + 1.f);
}

// ------------------------------------------------------------------
// K1: embedding gather  X0[t][b][e] = emb[words[b][t]][e]
// ------------------------------------------------------------------
__global__ void k_gather(const int* __restrict__ words,
                         const float* __restrict__ emb,
                         float* __restrict__ X0)
{
    int row = blockIdx.x;          // row = t*32 + b
    int t = row >> 5;
    int b = row & 31;
    int w = words[b * SEQ + t];
    const float* src = emb + (size_t)w * EDIM;
    float* dst = X0 + (size_t)row * EDIM;
    for (int e = threadIdx.x; e < EDIM; e += blockDim.x) dst[e] = src[e];
}

// ------------------------------------------------------------------
// K2/K4: C[M x N] = A[M x K] @ B[N x K]^T + bias[N]   (f32, tiled)
// ------------------------------------------------------------------
#define BM 64
#define BN 64
#define BK 32
#define LDT 72

__global__ __launch_bounds__(256)
void k_gemm_bias(const float* __restrict__ A,
                 const float* __restrict__ Bw,
                 const float* __restrict__ bias,
                 float* __restrict__ C,
                 int M, int N, int K)
{
    __shared__ __align__(16) float As[BK][LDT];
    __shared__ __align__(16) float Bs[BK][LDT];
    int tid = threadIdx.x;
    int tx = tid & 15, ty = tid >> 4;
    int bm = blockIdx.y * BM, bn = blockIdx.x * BN;
    float acc[4][4] = {};
    for (int k0 = 0; k0 < K; k0 += BK) {
#pragma unroll
        for (int i = 0; i < 8; ++i) {
            int idx = i * 256 + tid;
            int m = idx >> 5, k = idx & 31;
            bool ok = (k0 + k) < K;
            As[k][m] = ok ? A[(size_t)(bm + m) * K + k0 + k] : 0.f;
            Bs[k][m] = ok ? Bw[(size_t)(bn + m) * K + k0 + k] : 0.f;
        }
        __syncthreads();
#pragma unroll
        for (int kk = 0; kk < BK; ++kk) {
            float4 av = *(const float4*)&As[kk][ty * 4];
            float4 bv = *(const float4*)&Bs[kk][tx * 4];
            float a0 = av.x, a1 = av.y, a2 = av.z, a3 = av.w;
            float b0 = bv.x, b1 = bv.y, b2 = bv.z, b3 = bv.w;
            acc[0][0] += a0 * b0; acc[0][1] += a0 * b1; acc[0][2] += a0 * b2; acc[0][3] += a0 * b3;
            acc[1][0] += a1 * b0; acc[1][1] += a1 * b1; acc[1][2] += a1 * b2; acc[1][3] += a1 * b3;
            acc[2][0] += a2 * b0; acc[2][1] += a2 * b1; acc[2][2] += a2 * b2; acc[2][3] += a2 * b3;
            acc[3][0] += a3 * b0; acc[3][1] += a3 * b1; acc[3][2] += a3 * b2; acc[3][3] += a3 * b3;
        }
        __syncthreads();
    }
#pragma unroll
    for (int i = 0; i < 4; ++i) {
        int m = bm + ty * 4 + i;
#pragma unroll
        for (int j = 0; j < 4; ++j) {
            int n = bn + tx * 4 + j;
            C[(size_t)m * N + n] = acc[i][j] + bias[n];
        }
    }
}

// ------------------------------------------------------------------
// K3/K5: recurrent BiLSTM layer, fp16-packed U in registers.
// grid = 64 blocks (dir d, batch b). 512 threads (8 waves, 2/SIMD
// -> 256-VGPR budget via __launch_bounds__(512,2)).
// Worker w < 400 owns gate rows w and w+400: each row's 200 U
// weights packed into 100 half2 VGPRs -> 200 U-regs/thread.
// dot via v_dot2_f32_f16 (f32 accumulate). h kept in LDS as fp16,
// read as broadcast uint4 (same-address, conflict-free), shared
// between the thread's two rows. 2 acc chains per row for ILP.
// ------------------------------------------------------------------
#define REP100(X) \
    X(0)  X(1)  X(2)  X(3)  X(4)  X(5)  X(6)  X(7)  X(8)  X(9)  \
    X(10) X(11) X(12) X(13) X(14) X(15) X(16) X(17) X(18) X(19) \
    X(20) X(21) X(22) X(23) X(24) X(25) X(26) X(27) X(28) X(29) \
    X(30) X(31) X(32) X(33) X(34) X(35) X(36) X(37) X(38) X(39) \
    X(40) X(41) X(42) X(43) X(44) X(45) X(46) X(47) X(48) X(49) \
    X(50) X(51) X(52) X(53) X(54) X(55) X(56) X(57) X(58) X(59) \
    X(60) X(61) X(62) X(63) X(64) X(65) X(66) X(67) X(68) X(69) \
    X(70) X(71) X(72) X(73) X(74) X(75) X(76) X(77) X(78) X(79) \
    X(80) X(81) X(82) X(83) X(84) X(85) X(86) X(87) X(88) X(89) \
    X(90) X(91) X(92) X(93) X(94) X(95) X(96) X(97) X(98) X(99)

__global__ __launch_bounds__(512, 2)
void k_lstm(const float* __restrict__ Xg,
            const float* __restrict__ Whh,   // (2, 800, 200) f32
            float* __restrict__ Hout)
{
    int blk = blockIdx.x;      // 0..63
    int d = blk >> 5;          // direction
    int b = blk & 31;          // batch
    int w = threadIdx.x;
    bool worker = (w < 400);
    int rA = worker ? w : 399; // clamped for safe pointer arith
    int rB = rA + 400;

    __shared__ __align__(16) _Float16 h16[HDIM];   // h as fp16
    __shared__ float g_lds[G4];

    const float* UA = Whh + ((size_t)d * G4 + rA) * HDIM;
    const float* UB = Whh + ((size_t)d * G4 + rB) * HDIM;

#define UDECL(i) h2t a##i, b##i;
    REP100(UDECL)
#undef UDECL

    if (worker) {
#define ULOAD(i) { float2 fa_ = *(const float2*)&UA[2*(i)];                 \
                   h2t ta_; ta_.x = (_Float16)fa_.x; ta_.y = (_Float16)fa_.y; \
                   a##i = ta_;                                              \
                   float2 fb_ = *(const float2*)&UB[2*(i)];                 \
                   h2t tb_; tb_.x = (_Float16)fb_.x; tb_.y = (_Float16)fb_.y; \
                   b##i = tb_; }
        REP100(ULOAD)
#undef ULOAD
    }

    if (w < HDIM) h16[w] = (_Float16)0.f;
    float c = 0.f;

    const float* xgA = Xg + (size_t)b * NGATE + (size_t)d * G4 + rA;
    const float* xgB = xgA + 400;                 // rB = rA + 400
    const ptrdiff_t sstride = (ptrdiff_t)BATCH * NGATE;

    __syncthreads();

    int tt0 = d ? (SEQ - 1) : 0;
    float xgA_cur = 0.f, xgB_cur = 0.f;
    if (worker) {
        xgA_cur = xgA[(ptrdiff_t)tt0 * sstride];
        xgB_cur = xgB[(ptrdiff_t)tt0 * sstride];
    }

#define DOTQ(q, s, i0, i1, i2, i3) {                                        \
    uint4 hw_ = *(const uint4*)&h16[8*(q)];                                 \
    h2t h0_ = u2h(hw_.x), h1_ = u2h(hw_.y);                                 \
    h2t h2_ = u2h(hw_.z), h3_ = u2h(hw_.w);                                 \
    accA##s = dot2acc(a##i0, h0_, accA##s);                                 \
    accA##s = dot2acc(a##i1, h1_, accA##s);                                 \
    accA##s = dot2acc(a##i2, h2_, accA##s);                                 \
    accA##s = dot2acc(a##i3, h3_, accA##s);                                 \
    accB##s = dot2acc(b##i0, h0_, accB##s);                                 \
    accB##s = dot2acc(b##i1, h1_, accB##s);                                 \
    accB##s = dot2acc(b##i2, h2_, accB##s);                                 \
    accB##s = dot2acc(b##i3, h3_, accB##s); }

#pragma unroll 1
    for (int t = 0; t < SEQ; ++t) {
        int tt = d ? (SEQ - 1 - t) : t;
        if (worker) {
            float xgA_nxt = 0.f, xgB_nxt = 0.f;
            if (t + 1 < SEQ) {
                ptrdiff_t off = (ptrdiff_t)(d ? (SEQ - 2 - t) : (t + 1)) * sstride;
                xgA_nxt = xgA[off];
                xgB_nxt = xgB[off];
            }
            float accA0 = xgA_cur, accA1 = 0.f;
            float accB0 = xgB_cur, accB1 = 0.f;
            DOTQ( 0, 0,  0,  1,  2,  3)
            DOTQ( 1, 1,  4,  5,  6,  7)
            DOTQ( 2, 0,  8,  9, 10, 11)
            DOTQ( 3, 1, 12, 13, 14, 15)
            DOTQ( 4, 0, 16, 17, 18, 19)
            DOTQ( 5, 1, 20, 21, 22, 23)
            DOTQ( 6, 0, 24, 25, 26, 27)
            DOTQ( 7, 1, 28, 29, 30, 31)
            DOTQ( 8, 0, 32, 33, 34, 35)
            DOTQ( 9, 1, 36, 37, 38, 39)
            DOTQ(10, 0, 40, 41, 42, 43)
            DOTQ(11, 1, 44, 45, 46, 47)
            DOTQ(12, 0, 48, 49, 50, 51)
            DOTQ(13, 1, 52, 53, 54, 55)
            DOTQ(14, 0, 56, 57, 58, 59)
            DOTQ(15, 1, 60, 61, 62, 63)
            DOTQ(16, 0, 64, 65, 66, 67)
            DOTQ(17, 1, 68, 69, 70, 71)
            DOTQ(18, 0, 72, 73, 74, 75)
            DOTQ(19, 1, 76, 77, 78, 79)
            DOTQ(20, 0, 80, 81, 82, 83)
            DOTQ(21, 1, 84, 85, 86, 87)
            DOTQ(22, 0, 88, 89, 90, 91)
            DOTQ(23, 1, 92, 93, 94, 95)
            DOTQ(24, 0, 96, 97, 98, 99)
            g_lds[rA] = accA0 + accA1;
            g_lds[rB] = accB0 + accB1;
            xgA_cur = xgA_nxt;
            xgB_cur = xgB_nxt;
        }
        __syncthreads();
        if (w < HDIM) {
            float gi = g_lds[w];
            float gf = g_lds[HDIM + w];
            float gg = g_lds[2 * HDIM + w];
            float go = g_lds[3 * HDIM + w];
            float si = fast_sigmoid(gi);
            float sf = fast_sigmoid(gf);
            float so = fast_sigmoid(go);
            c = sf * c + si * fast_tanh(gg);
            float hh = so * fast_tanh(c);
            h16[w] = (_Float16)hh;
            Hout[((size_t)tt * BATCH + b) * (2 * HDIM) + d * HDIM + w] = hh;
        }
        __syncthreads();
    }
#undef DOTQ
}

// ------------------------------------------------------------------
// K6: out[b][s][o] = sigmoid(H1[s][b][:] . Wo[o][:] + bo[o])
// ------------------------------------------------------------------
__global__ void k_out(const float* __restrict__ H1,
                      const float* __restrict__ Wo,
                      const float* __restrict__ bo,
                      float* __restrict__ out)
{
    int idx = blockIdx.x * blockDim.x + threadIdx.x;
    if (idx >= BATCH * SEQ * 17) return;
    int o = idx % 17;
    int bs = idx / 17;
    int b = bs >> 7;      // /128
    int s = bs & 127;
    const float* hrow = H1 + ((size_t)(s * BATCH + b)) * (2 * HDIM);
    const float* wrow = Wo + (size_t)o * (2 * HDIM);
    float acc = bo[o];
#pragma unroll 4
    for (int j = 0; j < 2 * HDIM; ++j) acc += hrow[j] * wrow[j];
    out[idx] = 1.f / (1.f + __expf(-acc));
}

// ------------------------------------------------------------------
extern "C" void kernel_launch(void* const* d_in, const int* in_sizes, int n_in,
                              void* d_out, int out_size, void* d_ws, size_t ws_size,
                              hipStream_t stream)
{
    const int*   words = (const int*)d_in[0];
    // d_in[1] chars, d_in[2] lens: dead code in the reference
    const float* emb   = (const float*)d_in[3];
    // d_in[4..6]: char conv params, dead
    const float* Wih0  = (const float*)d_in[7];
    const float* Whh0  = (const float*)d_in[8];
    const float* b0    = (const float*)d_in[9];
    const float* Wih1  = (const float*)d_in[10];
    const float* Whh1  = (const float*)d_in[11];
    const float* b1    = (const float*)d_in[12];
    const float* Wo    = (const float*)d_in[13];
    const float* bo    = (const float*)d_in[14];
    float* out = (float*)d_out;

    char* ws = (char*)d_ws;
    const size_t X0_OFF = 0;
    const size_t XG_OFF = X0_OFF + (size_t)SEQ * BATCH * EDIM * 4;          // 4.9 MB
    const size_t H0_OFF = XG_OFF + (size_t)SEQ * BATCH * NGATE * 4;         // +26.2 MB
    const size_t H1_OFF = H0_OFF + (size_t)SEQ * BATCH * 2 * HDIM * 4;      // +6.6 MB
    float* X0 = (float*)(ws + X0_OFF);
    float* Xg = (float*)(ws + XG_OFF);
    float* H0 = (float*)(ws + H0_OFF);
    float* H1 = (float*)(ws + H1_OFF);

    // 1. gather embeddings -> X0 (S, B, 300)
    k_gather<<<SEQ * BATCH, 128, 0, stream>>>(words, emb, X0);

    // 2. layer-0 input GEMM: Xg = X0 @ Wih0^T + b0   (4096 x 1600, K=300)
    dim3 gemm_grid(NGATE / BN, (SEQ * BATCH) / BM);
    k_gemm_bias<<<gemm_grid, 256, 0, stream>>>(X0, Wih0, b0, Xg,
                                               SEQ * BATCH, NGATE, EDIM);

    // 3. layer-0 recurrence -> H0 (S, B, 400)
    k_lstm<<<64, 512, 0, stream>>>(Xg, Whh0, H0);

    // 4. layer-1 input GEMM: Xg = H0 @ Wih1^T + b1   (4096 x 1600, K=400)
    k_gemm_bias<<<gemm_grid, 256, 0, stream>>>(H0, Wih1, b1, Xg,
                                               SEQ * BATCH, NGATE, 2 * HDIM);

    // 5. layer-1 recurrence -> H1
    k_lstm<<<64, 512, 0, stream>>>(Xg, Whh1, H1);

    // 6. output head
    int nout = BATCH * SEQ * 17;
    k_out<<<(nout + 255) / 256, 256, 0, stream>>>(H1, Wo, bo, out);
}